// Round 26
// baseline (1929.428 us; speedup 1.0000x reference)
//
#include <hip/hip_runtime.h>
#include <math.h>

#define BB 64      // batch
#define SS 512     // seq len
#define HH 256     // hidden
#define NC 9       // classes
#define G4 1024    // 4*H gates (one direction)
#define VV 30000   // vocab

#define KLQ 9      // int8 k16 chunks cached in LDS = 144 KB; 7 streamed as int4

typedef _Float16 half2v __attribute__((ext_vector_type(2)));

// ---------- activations ----------
__device__ __forceinline__ float sigf(float x) {
    return 1.0f / (1.0f + __expf(-x));
}
__device__ __forceinline__ float tanhfast(float x) {
    float a = fabsf(x);
    float e = __expf(-2.0f * a);
    float t = (1.0f - e) / (1.0f + e);
    return copysignf(t, x);
}
__device__ __forceinline__ int dot16q(uint4 w, uint4 h, int acc) {
    acc = __builtin_amdgcn_sdot4((int)w.x, (int)h.x, acc, false);
    acc = __builtin_amdgcn_sdot4((int)w.y, (int)h.y, acc, false);
    acc = __builtin_amdgcn_sdot4((int)w.z, (int)h.z, acc, false);
    acc = __builtin_amdgcn_sdot4((int)w.w, (int)h.w, acc, false);
    return acc;
}
__device__ __forceinline__ ushort f16b(float x) {
    return __builtin_bit_cast(ushort, (_Float16)x);
}
__device__ __forceinline__ int pad4(int r) { return r + (r >> 3); }

// ---------- w_hh quantize: int8 (chunks 0..8) + signed-nibble int4 (9..15) ----------
// int4 layout per (dir,cc,j): 2 uints; u1 = {lo nib: k+0..3, hi nib: k+4..7},
// u2 = {lo: k+8..11, hi: k+12..15}. Decode: (u&0x0F0F0F0F)<<4 = 16*q (signed),
// u&0xF0F0F0F0 = 16*q_hi. Scale folds the 1/16.
__global__ void quant_whh(const float* __restrict__ whh, uint* __restrict__ wTq,
                          uint* __restrict__ wTq4,
                          float* __restrict__ swf, float* __restrict__ swf4) {
    const int row = blockIdx.x;        // 0..2047
    const int t = threadIdx.x;         // 0..63, owns k = 4t..4t+3
    float4 v = *(const float4*)(whh + (long)row * 256 + t * 4);
    float mloc = fmaxf(fmaxf(fabsf(v.x), fabsf(v.y)), fmaxf(fabsf(v.z), fabsf(v.w)));
    float mx = mloc;
    #pragma unroll
    for (int o = 32; o > 0; o >>= 1) mx = fmaxf(mx, __shfl_xor(mx, o));
    const int dir = row >> 10, j = row & 1023;
    // int8 all chunks (scan LDS-caches 0..8)
    {
        float inv = (mx > 0.f) ? 127.f / mx : 0.f;
        int q0 = (int)rintf(v.x * inv) & 255;
        int q1 = (int)rintf(v.y * inv) & 255;
        int q2 = (int)rintf(v.z * inv) & 255;
        int q3 = (int)rintf(v.w * inv) & 255;
        uint u = (uint)q0 | ((uint)q1 << 8) | ((uint)q2 << 16) | ((uint)q3 << 24);
        const int kc = t >> 2, l4 = t & 3;
        wTq[(((long)(dir * 16 + kc) * 1024 + j) << 2) + l4] = u;
    }
    // int4 signed nibbles for streamed k in [144,256)  (lanes t >= 36)
    float m4 = (t >= 36) ? mloc : 0.f;
    #pragma unroll
    for (int o = 32; o > 0; o >>= 1) m4 = fmaxf(m4, __shfl_xor(m4, o));
    float inv4 = (m4 > 0.f) ? 7.f / m4 : 0.f;
    int n0 = (int)rintf(v.x * inv4) & 0xF;
    int n1 = (int)rintf(v.y * inv4) & 0xF;
    int n2 = (int)rintf(v.z * inv4) & 0xF;
    int n3 = (int)rintf(v.w * inv4) & 0xF;
    uint part = (uint)n0 | ((uint)n1 << 8) | ((uint)n2 << 16) | ((uint)n3 << 24);
    uint other = __shfl(part, t ^ 1);
    if (!(t & 1) && t >= 36) {
        uint u = part | (other << 4);      // lo nibs from t, hi nibs from t+1
        int m = t >> 1;                    // 18..31
        int cc = (m >> 1) - 9;             // 0..6
        int pos = m & 1;                   // u1 / u2
        wTq4[(((long)(dir * 7 + cc) * 1024 + j) << 1) + pos] = u;
    }
    if (t == 0) {
        swf[row]  = (mx > 0.f) ? (mx / 127.f) * (1.f / 127.f) : 0.f;
        swf4[row] = (m4 > 0.f) ? (m4 / 7.f) * (1.f / 127.f) * (1.f / 16.f) : 0.f;
    }
}

// per-row int8 quantize, K = NP*64. mode 0: scale = mx/127 ; mode 1: mx/(127*127)
template <int NP>
__global__ void quant_rows(const float* __restrict__ in, unsigned char* __restrict__ out,
                           float* __restrict__ sc, int mode) {
    const int row = blockIdx.x;
    const int t = threadIdx.x;
    const int K = NP * 64;
    const float* src = in + (long)row * K + t * NP;
    float v[NP];
    float mx = 0.f;
    #pragma unroll
    for (int i = 0; i < NP; i++) { v[i] = src[i]; mx = fmaxf(mx, fabsf(v[i])); }
    #pragma unroll
    for (int o = 32; o > 0; o >>= 1) mx = fmaxf(mx, __shfl_xor(mx, o));
    float inv = (mx > 0.f) ? 127.f / mx : 0.f;
    unsigned char q[NP];
    #pragma unroll
    for (int i = 0; i < NP; i++) q[i] = (unsigned char)((int)rintf(v[i] * inv) & 255);
    unsigned char* dst = out + (long)row * K + t * NP;
    if (NP == 2) {
        *(ushort*)dst = *(ushort*)q;
    } else {
        *(uint*)dst = *(uint*)q;
        *(uint*)(dst + 4) = *(uint*)(q + 4);
    }
    if (t == 0) sc[row] = (mx <= 0.f) ? 0.f
                        : (mode == 0 ? mx / 127.f : mx / (127.f * 127.f));
}

// ---------- L0 gemm, full S, both dirs (proven round-25) ----------
__global__ __launch_bounds__(1024, 2) void gemm8e_k(
    const unsigned char* __restrict__ A8, const int* __restrict__ tok,
    const unsigned char* __restrict__ Wq, const float* __restrict__ sw,
    const float* __restrict__ swA, const float* __restrict__ bias,
    ushort* __restrict__ xg)
{
    __shared__ uint4 As[144], Bs[144];
    const int tid = threadIdx.x;
    const int m0 = blockIdx.x * 128;
    const int n0 = blockIdx.y * 128;
    const int d  = blockIdx.z;
    const unsigned char* W = Wq + (size_t)d * 1024 * 128;
    const float* swd = sw + d * 1024;
    const float* bd  = bias + d * 1024;
    ushort* outd = xg + (size_t)d * BB * SS * G4;

    const int lr = tid & 127;
    const int lpad = lr + (lr >> 3);
    const bool isA = tid < 128, isB = (tid >= 128 && tid < 256);
    const uint4* Ap = isA ? (const uint4*)(A8 + (long)tok[m0 + lr] * 128) : nullptr;
    const uint4* Wp = isB ? (const uint4*)(W + (long)(n0 + lr) * 128) : nullptr;
    const int tr = tid >> 5, tn = tid & 31;

    int acc[4][4];
    #pragma unroll
    for (int i = 0; i < 4; i++)
        #pragma unroll
        for (int j = 0; j < 4; j++) acc[i][j] = 0;

    #pragma unroll 1
    for (int k0 = 0; k0 < 8; k0++) {
        if (isA) As[lpad] = Ap[k0];
        else if (isB) Bs[lpad] = Wp[k0];
        __syncthreads();
        uint4 a[4], w[4];
        #pragma unroll
        for (int i = 0; i < 4; i++) {
            a[i] = As[pad4(tr * 4 + i)];
            w[i] = Bs[pad4(tn * 4 + i)];
        }
        #pragma unroll
        for (int i = 0; i < 4; i++)
            #pragma unroll
            for (int j = 0; j < 4; j++)
                acc[i][j] = dot16q(w[j], a[i], acc[i][j]);
        __syncthreads();
    }

    float sA[4];
    #pragma unroll
    for (int i = 0; i < 4; i++) sA[i] = swA[tok[m0 + tr * 4 + i]];
    float sW[4], bs[4];
    #pragma unroll
    for (int j = 0; j < 4; j++) {
        sW[j] = swd[n0 + tn * 4 + j];
        bs[j] = bd[n0 + tn * 4 + j];
    }
    #pragma unroll
    for (int i = 0; i < 4; i++) {
        ushort4 o;
        #pragma unroll
        for (int j = 0; j < 4; j++) {
            float r = fmaf((float)acc[i][j] * sA[i], sW[j], bs[j]);
            ((ushort*)&o)[j] = f16b(r);
        }
        *(ushort4*)(outd + (long)(m0 + tr * 4 + i) * G4 + n0 + tn * 4) = o;
    }
}

// ---------- L1 gemm, full S, both dirs (proven round-25) ----------
__global__ __launch_bounds__(1024, 2) void gemm8_k(
    const unsigned char* __restrict__ A8, const unsigned char* __restrict__ Wq,
    const float* __restrict__ sw, const float* __restrict__ bias,
    ushort* __restrict__ xg)
{
    __shared__ uint4 As[144], Bs[144];
    const int tid = threadIdx.x;
    const int m0 = blockIdx.x * 128;
    const int n0 = blockIdx.y * 128;
    const int d  = blockIdx.z;
    const unsigned char* W = Wq + (size_t)d * 1024 * 512;
    const float* swd = sw + d * 1024;
    const float* bd  = bias + d * 1024;
    ushort* outd = xg + (size_t)d * BB * SS * G4;

    const int lr = tid & 127;
    const int lpad = lr + (lr >> 3);
    const bool isA = tid < 128, isB = (tid >= 128 && tid < 256);
    const uint4* Ap = isA ? (const uint4*)(A8 + (long)(m0 + lr) * 512) : nullptr;
    const uint4* Wp = isB ? (const uint4*)(W + (long)(n0 + lr) * 512) : nullptr;
    const int tr = tid >> 5, tn = tid & 31;

    int acc[4][4];
    #pragma unroll
    for (int i = 0; i < 4; i++)
        #pragma unroll
        for (int j = 0; j < 4; j++) acc[i][j] = 0;

    #pragma unroll 1
    for (int k0 = 0; k0 < 32; k0++) {
        if (isA) As[lpad] = Ap[k0];
        else if (isB) Bs[lpad] = Wp[k0];
        __syncthreads();
        uint4 a[4], w[4];
        #pragma unroll
        for (int i = 0; i < 4; i++) {
            a[i] = As[pad4(tr * 4 + i)];
            w[i] = Bs[pad4(tn * 4 + i)];
        }
        #pragma unroll
        for (int i = 0; i < 4; i++)
            #pragma unroll
            for (int j = 0; j < 4; j++)
                acc[i][j] = dot16q(w[j], a[i], acc[i][j]);
        __syncthreads();
    }

    #pragma unroll
    for (int i = 0; i < 4; i++) {
        ushort4 o;
        #pragma unroll
        for (int j = 0; j < 4; j++) {
            float r = fmaf((float)acc[i][j], swd[n0 + tn * 4 + j], bd[n0 + tn * 4 + j]);
            ((ushort*)&o)[j] = f16b(r);
        }
        *(ushort4*)(outd + (long)(m0 + tr * 4 + i) * G4 + n0 + tn * 4) = o;
    }
}

// ---------- LSTM scan: int8 LDS-cached + signed-nibble int4 streamed ----------
__global__ __launch_bounds__(1024, 4) void lstm_qscan(
    const ushort* __restrict__ xg,    // [2][B*S][1024] f16, natural t order
    const uint* __restrict__ wTq,     // int8 [2][16][1024][4] (chunks 0..8 used)
    const uint* __restrict__ wTq4,    // int4 [2][7][1024][2]
    const float* __restrict__ swf,    // [2][1024]
    const float* __restrict__ swf4,   // [2][1024] (includes /16)
    const float* __restrict__ bhh2,   // [2][1024]
    ushort* __restrict__ hout,        // f16 H (layer 1)
    unsigned char* __restrict__ hout8,// int8 H (layer 0)
    int doW8)
{
    const int b = blockIdx.x;
    const int d = blockIdx.y;
    const int j = threadIdx.x;
    const ushort* xgd = xg + ((size_t)d * BB * SS + (size_t)b * SS) * G4 + j;
    const uint4* wTd = (const uint4*)wTq + (long)d * 16 * 1024;
    const uint2* w4d = (const uint2*)wTq4 + (long)d * 7 * 1024;

    __shared__ __align__(16) uint hq[2][64];   // int8 h packed
    __shared__ float gl[G4];                   // gate exchange
    __shared__ uint4 lwq[KLQ * 1024];          // 144 KB int8 weight cache

    #pragma unroll
    for (int kc = 0; kc < KLQ; kc++)
        lwq[kc * 1024 + j] = wTd[(long)kc * 1024 + j];

    const float bj = bhh2[d * G4 + j];
    const float s8 = swf[d * G4 + j];
    const float s4 = swf4[d * G4 + j];
    float c_reg = 0.f;
    if (j < HH) ((char*)hq[0])[j] = 0;
    __syncthreads();

    #pragma unroll 1
    for (int tc = 0; tc < SS; ++tc) {
        const int rb = tc & 1;
        const int t = d ? (SS - 1 - tc) : tc;
        const uint4* hc = (const uint4*)hq[rb];
        int isum8 = 0;
        #pragma unroll
        for (int kc = 0; kc < KLQ; kc++)
            isum8 = dot16q(lwq[kc * 1024 + j], hc[kc], isum8);
        int isum4 = 0;
        #pragma unroll
        for (int cc = 0; cc < 7; cc++) {
            uint2 u = w4d[(long)cc * 1024 + j];
            uint4 h = hc[9 + cc];
            isum4 = __builtin_amdgcn_sdot4((int)((u.x & 0x0F0F0F0Fu) << 4), (int)h.x, isum4, false);
            isum4 = __builtin_amdgcn_sdot4((int)(u.x & 0xF0F0F0F0u),        (int)h.y, isum4, false);
            isum4 = __builtin_amdgcn_sdot4((int)((u.y & 0x0F0F0F0Fu) << 4), (int)h.z, isum4, false);
            isum4 = __builtin_amdgcn_sdot4((int)(u.y & 0xF0F0F0F0u),        (int)h.w, isum4, false);
        }

        float xv = (float)__builtin_bit_cast(_Float16, xgd[(long)t * G4]);
        gl[j] = fmaf((float)isum4, s4, fmaf((float)isum8, s8, xv + bj));
        __syncthreads();
        if (j < HH) {
            float gi = gl[j], gf = gl[j + 256], gg = gl[j + 512], go = gl[j + 768];
            c_reg = sigf(gf) * c_reg + sigf(gi) * tanhfast(gg);
            float h = sigf(go) * tanhfast(c_reg);
            int qh = __float2int_rn(h * 127.f);
            ((char*)hq[rb ^ 1])[j] = (char)qh;
            if (doW8) hout8[((long)(b * SS + t)) * 512 + d * HH + j] = (unsigned char)(char)qh;
            else      hout [((long)(b * SS + t)) * 512 + d * HH + j] = f16b(h);
        }
        __syncthreads();
    }
}

// ---------- emissions (f16 h) ----------
__global__ __launch_bounds__(256) void emissions_k16(
    const ushort* __restrict__ h1, const float* __restrict__ clsw,
    const float* __restrict__ clsb, float* __restrict__ em)
{
    long u = (long)blockIdx.x * 256 + threadIdx.x;
    if (u >= (long)BB * SS * NC) return;
    int c = (int)(u % NC);
    long m = u / NC;
    const uint* hr = (const uint*)(h1 + m * 512);
    const float2* wr = (const float2*)(clsw + (long)c * 512);
    float s0 = 0, s1 = 0;
    #pragma unroll 8
    for (int q = 0; q < 256; q += 2) {
        half2v h0 = __builtin_bit_cast(half2v, hr[q]);
        half2v h1v = __builtin_bit_cast(half2v, hr[q + 1]);
        float2 w0 = wr[q], w1 = wr[q + 1];
        s0 += (float)h0.x * w0.x + (float)h0.y * w0.y;
        s1 += (float)h1v.x * w1.x + (float)h1v.y * w1.y;
    }
    em[u] = s0 + s1 + clsb[c];
}

// ---------- fused CRF llh (blocks 0..63) + Viterbi (blocks 64..127) ----------
__global__ __launch_bounds__(64) void crfvit_k(
    const float* __restrict__ em, const int* __restrict__ labels,
    const int* __restrict__ mask, const float* __restrict__ start,
    const float* __restrict__ endt, const float* __restrict__ trans,
    float* __restrict__ llh, float* __restrict__ outp)
{
    __shared__ unsigned char bp[SS][NC];
    const int j = threadIdx.x;
    const bool act = j < NC;
    if (blockIdx.x < BB) {
        const int b = blockIdx.x;
        float tcol[NC];
        #pragma unroll
        for (int i = 0; i < NC; i++) tcol[i] = act ? trans[i * NC + j] : 0.f;
        const float* emb_ = em + (long)b * SS * NC;
        const int* lb = labels + b * SS;
        const int* mk = mask + b * SS;
        float alpha = act ? (start[j] + emb_[j]) : -1e30f;

        float num = 0.f;
        int msum = 0;
        for (int t = j; t < SS; t += 64) msum += (mk[t] != 0);
        for (int t = 1 + j; t < SS; t += 64) {
            float m = (float)mk[t];
            num += m * (trans[lb[t - 1] * NC + lb[t]] + emb_[t * NC + lb[t]]);
        }
        for (int o = 32; o > 0; o >>= 1) {
            num  += __shfl_down(num, o);
            msum += __shfl_down(msum, o);
        }
        msum = __shfl(msum, 0);

        for (int t = 1; t < SS; t++) {
            int m = mk[t];
            float emj = act ? emb_[t * NC + j] : 0.f;
            float v[NC];
            float mx = -1e30f;
            #pragma unroll
            for (int i = 0; i < NC; i++) {
                v[i] = __shfl(alpha, i) + tcol[i];
                mx = fmaxf(mx, v[i]);
            }
            float sum = 0.f;
            #pragma unroll
            for (int i = 0; i < NC; i++) sum += __expf(v[i] - mx);
            float nxt = mx + __logf(sum) + emj;
            if (m > 0 && act) alpha = nxt;
        }
        float fin = act ? alpha + endt[j] : -1e30f;
        float mx = -1e30f;
        #pragma unroll
        for (int i = 0; i < NC; i++) mx = fmaxf(mx, __shfl(fin, i));
        float s = 0.f;
        #pragma unroll
        for (int i = 0; i < NC; i++) s += __expf(__shfl(fin, i) - mx);
        float den = mx + __logf(s);
        if (j == 0) {
            int last_idx = msum - 1;
            float numer = num + start[lb[0]] + emb_[lb[0]] + endt[lb[last_idx]];
            llh[b] = numer - den;
        }
    } else {
        const int b = blockIdx.x - BB;
        float tcol[NC];
        #pragma unroll
        for (int i = 0; i < NC; i++) tcol[i] = act ? trans[i * NC + j] : 0.f;
        const float* emb_ = em + (long)b * SS * NC;
        const int* mk = mask + b * SS;
        float score = act ? (start[j] + emb_[j]) : -1e30f;

        for (int t = 1; t < SS; t++) {
            float best = 0.f;
            int bi = 0;
            #pragma unroll
            for (int i = 0; i < NC; i++) {
                float vv = __shfl(score, i) + tcol[i];
                if (i == 0 || vv > best) { best = vv; bi = i; }   // first-max (jnp.argmax)
            }
            int m = mk[t];
            float nxt = best + (act ? emb_[t * NC + j] : 0.f);
            if (act) {
                if (m > 0) { score = nxt; bp[t][j] = (unsigned char)bi; }
                else       { bp[t][j] = (unsigned char)j; }
            }
        }
        float fin = act ? score + endt[j] : -1e30f;
        float bestf = 0.f;
        int last = 0;
        #pragma unroll
        for (int i = 0; i < NC; i++) {
            float vv = __shfl(fin, i);
            if (i == 0 || vv > bestf) { bestf = vv; last = i; }
        }
        __syncthreads();
        if (j == 0) {
            int cur = last;
            outp[1 + (long)b * SS + (SS - 1)] = (float)cur;
            for (int t = SS - 1; t >= 1; t--) {
                cur = bp[t][cur];
                outp[1 + (long)b * SS + (t - 1)] = (float)cur;
            }
        }
    }
}

__global__ __launch_bounds__(64) void loss_k(const float* __restrict__ llh, float* __restrict__ out) {
    int j = threadIdx.x;
    float v = llh[j];
    for (int o = 32; o > 0; o >>= 1) v += __shfl_down(v, o);
    if (j == 0) out[0] = -v / 64.0f;
}

extern "C" void kernel_launch(void* const* d_in, const int* in_sizes, int n_in,
                              void* d_out, int out_size, void* d_ws, size_t ws_size,
                              hipStream_t stream) {
    const int*   tok    = (const int*)d_in[0];
    const int*   lab    = (const int*)d_in[1];
    const int*   msk    = (const int*)d_in[2];
    const float* emb    = (const float*)d_in[3];
    const float* w_ih0  = (const float*)d_in[4];
    const float* w_hh0  = (const float*)d_in[5];
    const float* b_ih0  = (const float*)d_in[6];
    const float* b_hh0  = (const float*)d_in[7];
    const float* w_ih1  = (const float*)d_in[8];
    const float* w_hh1  = (const float*)d_in[9];
    const float* b_ih1  = (const float*)d_in[10];
    const float* b_hh1  = (const float*)d_in[11];
    const float* clsw   = (const float*)d_in[12];
    const float* clsb   = (const float*)d_in[13];
    const float* startt = (const float*)d_in[14];
    const float* endt   = (const float*)d_in[15];
    const float* transm = (const float*)d_in[16];
    float* out = (float*)d_out;

    // ---- workspace carve (f32 units); ~193 MB ----
    size_t nH8  = (size_t)BB * SS * 512 / 4;        // int8 H0
    size_t nHh  = (size_t)BB * SS * 512 / 2;        // f16 H1
    size_t nXG  = (size_t)2 * BB * SS * G4 / 2;     // f16 xg, both dirs, full S
    size_t nWQ  = (size_t)2 * 16 * 1024 * 4;        // whh int8 (uints) per layer
    size_t nW4  = (size_t)2 * 7 * 1024 * 2;         // whh int4 (uints) per layer
    size_t nSW  = (size_t)2 * 1024;
    size_t nWQ1 = (size_t)2048 * 512 / 4;
    size_t nWQ0 = (size_t)2048 * 128 / 4;
    size_t nE8  = (size_t)VV * 128 / 4;
    size_t nEM  = (size_t)BB * SS * NC;

    float* H08f = (float*)d_ws;
    float* H1f  = H08f + nH8;
    float* XGf  = H1f + nHh;
    float* WQ0  = XGf + nXG;
    float* WQ1w = WQ0 + nWQ;
    float* W40  = WQ1w + nWQ;
    float* W41  = W40 + nW4;
    float* SW0  = W41 + nW4;
    float* SW1  = SW0 + nSW;
    float* S40  = SW1 + nSW;
    float* S41  = S40 + nSW;
    float* WQI1 = S41 + nSW;
    float* SWI1 = WQI1 + nWQ1;
    float* WQI0 = SWI1 + 2048;
    float* SWI0 = WQI0 + nWQ0;
    float* EMB8 = SWI0 + 2048;
    float* SA   = EMB8 + nE8;
    float* EM   = SA + VV;
    float* LLH  = EM + nEM;

    unsigned char* H08   = (unsigned char*)H08f;
    ushort*        H1h   = (ushort*)H1f;
    ushort*        XG    = (ushort*)XGf;
    unsigned char* WQI1b = (unsigned char*)WQI1;
    unsigned char* WQI0b = (unsigned char*)WQI0;
    unsigned char* EMB8b = (unsigned char*)EMB8;

    // ---- preprocessing ----
    quant_whh<<<2048, 64, 0, stream>>>(w_hh0, (uint*)WQ0, (uint*)W40, SW0, S40);
    quant_whh<<<2048, 64, 0, stream>>>(w_hh1, (uint*)WQ1w, (uint*)W41, SW1, S41);
    quant_rows<8><<<2048, 64, 0, stream>>>(w_ih1, WQI1b, SWI1, 1);
    quant_rows<2><<<2048, 64, 0, stream>>>(w_ih0, WQI0b, SWI0, 0);
    quant_rows<2><<<VV, 64, 0, stream>>>(emb, EMB8b, SA, 0);

    dim3 gg(BB * SS / 128, G4 / 128, 2);   // (256, 8, 2)
    dim3 rg(BB, 2);                         // 128 blocks, 1024 threads

    // ---- layer 0: full-S gemm, then full-S scan (emits int8 H0) ----
    gemm8e_k<<<gg, 1024, 0, stream>>>(EMB8b, tok, WQI0b, SWI0, SA, b_ih0, XG);
    lstm_qscan<<<rg, 1024, 0, stream>>>(XG, (const uint*)WQ0, (const uint*)W40,
                                        SW0, S40, b_hh0, H1h, H08, 1);
    // ---- layer 1: full-S gemm from H08, then full-S scan (emits f16 H1) ----
    gemm8_k<<<gg, 1024, 0, stream>>>(H08, WQI1b, SWI1, b_ih1, XG);
    lstm_qscan<<<rg, 1024, 0, stream>>>(XG, (const uint*)WQ1w, (const uint*)W41,
                                        SW1, S41, b_hh1, H1h, H08, 0);

    // ---- tail ----
    emissions_k16<<<((BB * SS * NC) + 255) / 256, 256, 0, stream>>>(H1h, clsw, clsb, EM);
    crfvit_k<<<2 * BB, 64, 0, stream>>>(EM, lab, msk, startt, endt, transm, LLH, out);
    loss_k<<<1, 64, 0, stream>>>(LLH, out);
}

// Round 27
// 1906.774 us; speedup vs baseline: 1.0119x; 1.0119x over previous
//
#include <hip/hip_runtime.h>
#include <math.h>

#define BB 64      // batch
#define SS 512     // seq len
#define HH 256     // hidden
#define NC 9       // classes
#define G4 1024    // 4*H gates (one direction)
#define VV 30000   // vocab

#define KLQ 9      // int8 k16 chunks cached in LDS = 144 KB; 7 streamed as int4

typedef _Float16 half2v __attribute__((ext_vector_type(2)));

// ---------- activations ----------
__device__ __forceinline__ float sigf(float x) {
    return 1.0f / (1.0f + __expf(-x));
}
__device__ __forceinline__ float tanhfast(float x) {
    float a = fabsf(x);
    float e = __expf(-2.0f * a);
    float t = (1.0f - e) / (1.0f + e);
    return copysignf(t, x);
}
__device__ __forceinline__ int dot16q(uint4 w, uint4 h, int acc) {
    acc = __builtin_amdgcn_sdot4((int)w.x, (int)h.x, acc, false);
    acc = __builtin_amdgcn_sdot4((int)w.y, (int)h.y, acc, false);
    acc = __builtin_amdgcn_sdot4((int)w.z, (int)h.z, acc, false);
    acc = __builtin_amdgcn_sdot4((int)w.w, (int)h.w, acc, false);
    return acc;
}
__device__ __forceinline__ ushort f16b(float x) {
    return __builtin_bit_cast(ushort, (_Float16)x);
}
__device__ __forceinline__ int pad4(int r) { return r + (r >> 3); }

// LDS-only barrier: order LDS writes->reads without draining vmcnt
// (avoids waiting for hout global-store retirement every step).
__device__ __forceinline__ void ldsbar() {
    asm volatile("s_waitcnt lgkmcnt(0)" ::: "memory");
    __builtin_amdgcn_s_barrier();
}

// ---------- preprocessing device bodies ----------
__device__ void quant_whh_dev(const float* __restrict__ whh, uint* __restrict__ wTq,
                              uint* __restrict__ wTq4,
                              float* __restrict__ swf, float* __restrict__ swf4, int row) {
    const int t = threadIdx.x;
    float4 v = *(const float4*)(whh + (long)row * 256 + t * 4);
    float mloc = fmaxf(fmaxf(fabsf(v.x), fabsf(v.y)), fmaxf(fabsf(v.z), fabsf(v.w)));
    float mx = mloc;
    #pragma unroll
    for (int o = 32; o > 0; o >>= 1) mx = fmaxf(mx, __shfl_xor(mx, o));
    const int dir = row >> 10, j = row & 1023;
    {
        float inv = (mx > 0.f) ? 127.f / mx : 0.f;
        int q0 = (int)rintf(v.x * inv) & 255;
        int q1 = (int)rintf(v.y * inv) & 255;
        int q2 = (int)rintf(v.z * inv) & 255;
        int q3 = (int)rintf(v.w * inv) & 255;
        uint u = (uint)q0 | ((uint)q1 << 8) | ((uint)q2 << 16) | ((uint)q3 << 24);
        const int kc = t >> 2, l4 = t & 3;
        wTq[(((long)(dir * 16 + kc) * 1024 + j) << 2) + l4] = u;
    }
    float m4 = (t >= 36) ? mloc : 0.f;
    #pragma unroll
    for (int o = 32; o > 0; o >>= 1) m4 = fmaxf(m4, __shfl_xor(m4, o));
    float inv4 = (m4 > 0.f) ? 7.f / m4 : 0.f;
    int n0 = (int)rintf(v.x * inv4) & 0xF;
    int n1 = (int)rintf(v.y * inv4) & 0xF;
    int n2 = (int)rintf(v.z * inv4) & 0xF;
    int n3 = (int)rintf(v.w * inv4) & 0xF;
    uint part = (uint)n0 | ((uint)n1 << 8) | ((uint)n2 << 16) | ((uint)n3 << 24);
    uint other = __shfl(part, t ^ 1);
    if (!(t & 1) && t >= 36) {
        uint u = part | (other << 4);
        int m = t >> 1;
        int cc = (m >> 1) - 9;
        int pos = m & 1;
        wTq4[(((long)(dir * 7 + cc) * 1024 + j) << 1) + pos] = u;
    }
    if (t == 0) {
        swf[row]  = (mx > 0.f) ? (mx / 127.f) * (1.f / 127.f) : 0.f;
        swf4[row] = (m4 > 0.f) ? (m4 / 7.f) * (1.f / 127.f) * (1.f / 16.f) : 0.f;
    }
}

template <int NP>
__device__ void quant_rows_dev(const float* __restrict__ in, unsigned char* __restrict__ out,
                               float* __restrict__ sc, int mode, int row) {
    const int t = threadIdx.x;
    const int K = NP * 64;
    const float* src = in + (long)row * K + t * NP;
    float v[NP];
    float mx = 0.f;
    #pragma unroll
    for (int i = 0; i < NP; i++) { v[i] = src[i]; mx = fmaxf(mx, fabsf(v[i])); }
    #pragma unroll
    for (int o = 32; o > 0; o >>= 1) mx = fmaxf(mx, __shfl_xor(mx, o));
    float inv = (mx > 0.f) ? 127.f / mx : 0.f;
    unsigned char q[NP];
    #pragma unroll
    for (int i = 0; i < NP; i++) q[i] = (unsigned char)((int)rintf(v[i] * inv) & 255);
    unsigned char* dst = out + (long)row * K + t * NP;
    if (NP == 2) {
        *(ushort*)dst = *(ushort*)q;
    } else {
        *(uint*)dst = *(uint*)q;
        *(uint*)(dst + 4) = *(uint*)(q + 4);
    }
    if (t == 0) sc[row] = (mx <= 0.f) ? 0.f
                        : (mode == 0 ? mx / 127.f : mx / (127.f * 127.f));
}

// ---------- fused preprocessing: one dispatch, role by blockIdx ----------
__global__ __launch_bounds__(64) void preproc_k(
    const float* __restrict__ whh0, const float* __restrict__ whh1,
    const float* __restrict__ wih1, const float* __restrict__ wih0,
    const float* __restrict__ emb,
    uint* WQ0, uint* W40, float* SW0, float* S40,
    uint* WQ1, uint* W41, float* SW1, float* S41,
    unsigned char* WQI1, float* SWI1,
    unsigned char* WQI0, float* SWI0,
    unsigned char* EMB8, float* SA)
{
    int bid = blockIdx.x;
    if (bid < 2048) { quant_whh_dev(whh0, WQ0, W40, SW0, S40, bid); return; }
    bid -= 2048;
    if (bid < 2048) { quant_whh_dev(whh1, WQ1, W41, SW1, S41, bid); return; }
    bid -= 2048;
    if (bid < 2048) { quant_rows_dev<8>(wih1, WQI1, SWI1, 1, bid); return; }
    bid -= 2048;
    if (bid < 2048) { quant_rows_dev<2>(wih0, WQI0, SWI0, 0, bid); return; }
    bid -= 2048;
    quant_rows_dev<2>(emb, EMB8, SA, 0, bid);
}

// ---------- L0 gemm, full S, both dirs (proven round-25) ----------
__global__ __launch_bounds__(1024, 2) void gemm8e_k(
    const unsigned char* __restrict__ A8, const int* __restrict__ tok,
    const unsigned char* __restrict__ Wq, const float* __restrict__ sw,
    const float* __restrict__ swA, const float* __restrict__ bias,
    ushort* __restrict__ xg)
{
    __shared__ uint4 As[144], Bs[144];
    const int tid = threadIdx.x;
    const int m0 = blockIdx.x * 128;
    const int n0 = blockIdx.y * 128;
    const int d  = blockIdx.z;
    const unsigned char* W = Wq + (size_t)d * 1024 * 128;
    const float* swd = sw + d * 1024;
    const float* bd  = bias + d * 1024;
    ushort* outd = xg + (size_t)d * BB * SS * G4;

    const int lr = tid & 127;
    const int lpad = lr + (lr >> 3);
    const bool isA = tid < 128, isB = (tid >= 128 && tid < 256);
    const uint4* Ap = isA ? (const uint4*)(A8 + (long)tok[m0 + lr] * 128) : nullptr;
    const uint4* Wp = isB ? (const uint4*)(W + (long)(n0 + lr) * 128) : nullptr;
    const int tr = tid >> 5, tn = tid & 31;

    int acc[4][4];
    #pragma unroll
    for (int i = 0; i < 4; i++)
        #pragma unroll
        for (int j = 0; j < 4; j++) acc[i][j] = 0;

    #pragma unroll 1
    for (int k0 = 0; k0 < 8; k0++) {
        if (isA) As[lpad] = Ap[k0];
        else if (isB) Bs[lpad] = Wp[k0];
        __syncthreads();
        uint4 a[4], w[4];
        #pragma unroll
        for (int i = 0; i < 4; i++) {
            a[i] = As[pad4(tr * 4 + i)];
            w[i] = Bs[pad4(tn * 4 + i)];
        }
        #pragma unroll
        for (int i = 0; i < 4; i++)
            #pragma unroll
            for (int j = 0; j < 4; j++)
                acc[i][j] = dot16q(w[j], a[i], acc[i][j]);
        __syncthreads();
    }

    float sA[4];
    #pragma unroll
    for (int i = 0; i < 4; i++) sA[i] = swA[tok[m0 + tr * 4 + i]];
    float sW[4], bs[4];
    #pragma unroll
    for (int j = 0; j < 4; j++) {
        sW[j] = swd[n0 + tn * 4 + j];
        bs[j] = bd[n0 + tn * 4 + j];
    }
    #pragma unroll
    for (int i = 0; i < 4; i++) {
        ushort4 o;
        #pragma unroll
        for (int j = 0; j < 4; j++) {
            float r = fmaf((float)acc[i][j] * sA[i], sW[j], bs[j]);
            ((ushort*)&o)[j] = f16b(r);
        }
        *(ushort4*)(outd + (long)(m0 + tr * 4 + i) * G4 + n0 + tn * 4) = o;
    }
}

// ---------- L1 gemm, full S, both dirs (proven round-25) ----------
__global__ __launch_bounds__(1024, 2) void gemm8_k(
    const unsigned char* __restrict__ A8, const unsigned char* __restrict__ Wq,
    const float* __restrict__ sw, const float* __restrict__ bias,
    ushort* __restrict__ xg)
{
    __shared__ uint4 As[144], Bs[144];
    const int tid = threadIdx.x;
    const int m0 = blockIdx.x * 128;
    const int n0 = blockIdx.y * 128;
    const int d  = blockIdx.z;
    const unsigned char* W = Wq + (size_t)d * 1024 * 512;
    const float* swd = sw + d * 1024;
    const float* bd  = bias + d * 1024;
    ushort* outd = xg + (size_t)d * BB * SS * G4;

    const int lr = tid & 127;
    const int lpad = lr + (lr >> 3);
    const bool isA = tid < 128, isB = (tid >= 128 && tid < 256);
    const uint4* Ap = isA ? (const uint4*)(A8 + (long)(m0 + lr) * 512) : nullptr;
    const uint4* Wp = isB ? (const uint4*)(W + (long)(n0 + lr) * 512) : nullptr;
    const int tr = tid >> 5, tn = tid & 31;

    int acc[4][4];
    #pragma unroll
    for (int i = 0; i < 4; i++)
        #pragma unroll
        for (int j = 0; j < 4; j++) acc[i][j] = 0;

    #pragma unroll 1
    for (int k0 = 0; k0 < 32; k0++) {
        if (isA) As[lpad] = Ap[k0];
        else if (isB) Bs[lpad] = Wp[k0];
        __syncthreads();
        uint4 a[4], w[4];
        #pragma unroll
        for (int i = 0; i < 4; i++) {
            a[i] = As[pad4(tr * 4 + i)];
            w[i] = Bs[pad4(tn * 4 + i)];
        }
        #pragma unroll
        for (int i = 0; i < 4; i++)
            #pragma unroll
            for (int j = 0; j < 4; j++)
                acc[i][j] = dot16q(w[j], a[i], acc[i][j]);
        __syncthreads();
    }

    #pragma unroll
    for (int i = 0; i < 4; i++) {
        ushort4 o;
        #pragma unroll
        for (int j = 0; j < 4; j++) {
            float r = fmaf((float)acc[i][j], swd[n0 + tn * 4 + j], bd[n0 + tn * 4 + j]);
            ((ushort*)&o)[j] = f16b(r);
        }
        *(ushort4*)(outd + (long)(m0 + tr * 4 + i) * G4 + n0 + tn * 4) = o;
    }
}

// ---------- LSTM scan: int8 LDS-cached + int4 streamed, LDS-only barriers ----------
__global__ __launch_bounds__(1024, 4) void lstm_qscan(
    const ushort* __restrict__ xg,    // [2][B*S][1024] f16, natural t order
    const uint* __restrict__ wTq,     // int8 [2][16][1024][4] (chunks 0..8 used)
    const uint* __restrict__ wTq4,    // int4 [2][7][1024][2]
    const float* __restrict__ swf,    // [2][1024]
    const float* __restrict__ swf4,   // [2][1024] (includes /16)
    const float* __restrict__ bhh2,   // [2][1024]
    ushort* __restrict__ hout,        // f16 H (layer 1)
    unsigned char* __restrict__ hout8,// int8 H (layer 0)
    int doW8)
{
    const int b = blockIdx.x;
    const int d = blockIdx.y;
    const int j = threadIdx.x;
    const ushort* xgd = xg + ((size_t)d * BB * SS + (size_t)b * SS) * G4 + j;
    const uint4* wTd = (const uint4*)wTq + (long)d * 16 * 1024;
    const uint2* w4d = (const uint2*)wTq4 + (long)d * 7 * 1024;

    __shared__ __align__(16) uint hq[2][64];   // int8 h packed
    __shared__ float gl[G4];                   // gate exchange
    __shared__ uint4 lwq[KLQ * 1024];          // 144 KB int8 weight cache

    #pragma unroll
    for (int kc = 0; kc < KLQ; kc++)
        lwq[kc * 1024 + j] = wTd[(long)kc * 1024 + j];

    const float bj = bhh2[d * G4 + j];
    const float s8 = swf[d * G4 + j];
    const float s4 = swf4[d * G4 + j];
    float c_reg = 0.f;
    if (j < HH) ((char*)hq[0])[j] = 0;
    __syncthreads();

    #pragma unroll 1
    for (int tc = 0; tc < SS; ++tc) {
        const int rb = tc & 1;
        const int t = d ? (SS - 1 - tc) : tc;
        const uint4* hc = (const uint4*)hq[rb];
        int isum8 = 0;
        #pragma unroll
        for (int kc = 0; kc < KLQ; kc++)
            isum8 = dot16q(lwq[kc * 1024 + j], hc[kc], isum8);
        int isum4 = 0;
        #pragma unroll
        for (int cc = 0; cc < 7; cc++) {
            uint2 u = w4d[(long)cc * 1024 + j];
            uint4 h = hc[9 + cc];
            isum4 = __builtin_amdgcn_sdot4((int)((u.x & 0x0F0F0F0Fu) << 4), (int)h.x, isum4, false);
            isum4 = __builtin_amdgcn_sdot4((int)(u.x & 0xF0F0F0F0u),        (int)h.y, isum4, false);
            isum4 = __builtin_amdgcn_sdot4((int)((u.y & 0x0F0F0F0Fu) << 4), (int)h.z, isum4, false);
            isum4 = __builtin_amdgcn_sdot4((int)(u.y & 0xF0F0F0F0u),        (int)h.w, isum4, false);
        }

        float xv = (float)__builtin_bit_cast(_Float16, xgd[(long)t * G4]);
        gl[j] = fmaf((float)isum4, s4, fmaf((float)isum8, s8, xv + bj));
        ldsbar();                            // order gl writes -> reads (LDS only)
        if (j < HH) {
            float gi = gl[j], gf = gl[j + 256], gg = gl[j + 512], go = gl[j + 768];
            c_reg = sigf(gf) * c_reg + sigf(gi) * tanhfast(gg);
            float h = sigf(go) * tanhfast(c_reg);
            int qh = __float2int_rn(h * 127.f);
            ((char*)hq[rb ^ 1])[j] = (char)qh;
            if (doW8) hout8[((long)(b * SS + t)) * 512 + d * HH + j] = (unsigned char)(char)qh;
            else      hout [((long)(b * SS + t)) * 512 + d * HH + j] = f16b(h);
        }
        ldsbar();                            // order hq writes -> next-step reads
    }
}

// ---------- emissions (f16 h) ----------
__global__ __launch_bounds__(256) void emissions_k16(
    const ushort* __restrict__ h1, const float* __restrict__ clsw,
    const float* __restrict__ clsb, float* __restrict__ em)
{
    long u = (long)blockIdx.x * 256 + threadIdx.x;
    if (u >= (long)BB * SS * NC) return;
    int c = (int)(u % NC);
    long m = u / NC;
    const uint* hr = (const uint*)(h1 + m * 512);
    const float2* wr = (const float2*)(clsw + (long)c * 512);
    float s0 = 0, s1 = 0;
    #pragma unroll 8
    for (int q = 0; q < 256; q += 2) {
        half2v h0 = __builtin_bit_cast(half2v, hr[q]);
        half2v h1v = __builtin_bit_cast(half2v, hr[q + 1]);
        float2 w0 = wr[q], w1 = wr[q + 1];
        s0 += (float)h0.x * w0.x + (float)h0.y * w0.y;
        s1 += (float)h1v.x * w1.x + (float)h1v.y * w1.y;
    }
    em[u] = s0 + s1 + clsb[c];
}

// ---------- fused CRF llh (blocks 0..63) + Viterbi (blocks 64..127) ----------
__global__ __launch_bounds__(64) void crfvit_k(
    const float* __restrict__ em, const int* __restrict__ labels,
    const int* __restrict__ mask, const float* __restrict__ start,
    const float* __restrict__ endt, const float* __restrict__ trans,
    float* __restrict__ llh, float* __restrict__ outp)
{
    __shared__ unsigned char bp[SS][NC];
    const int j = threadIdx.x;
    const bool act = j < NC;
    if (blockIdx.x < BB) {
        const int b = blockIdx.x;
        float tcol[NC];
        #pragma unroll
        for (int i = 0; i < NC; i++) tcol[i] = act ? trans[i * NC + j] : 0.f;
        const float* emb_ = em + (long)b * SS * NC;
        const int* lb = labels + b * SS;
        const int* mk = mask + b * SS;
        float alpha = act ? (start[j] + emb_[j]) : -1e30f;

        float num = 0.f;
        int msum = 0;
        for (int t = j; t < SS; t += 64) msum += (mk[t] != 0);
        for (int t = 1 + j; t < SS; t += 64) {
            float m = (float)mk[t];
            num += m * (trans[lb[t - 1] * NC + lb[t]] + emb_[t * NC + lb[t]]);
        }
        for (int o = 32; o > 0; o >>= 1) {
            num  += __shfl_down(num, o);
            msum += __shfl_down(msum, o);
        }
        msum = __shfl(msum, 0);

        for (int t = 1; t < SS; t++) {
            int m = mk[t];
            float emj = act ? emb_[t * NC + j] : 0.f;
            float v[NC];
            float mx = -1e30f;
            #pragma unroll
            for (int i = 0; i < NC; i++) {
                v[i] = __shfl(alpha, i) + tcol[i];
                mx = fmaxf(mx, v[i]);
            }
            float sum = 0.f;
            #pragma unroll
            for (int i = 0; i < NC; i++) sum += __expf(v[i] - mx);
            float nxt = mx + __logf(sum) + emj;
            if (m > 0 && act) alpha = nxt;
        }
        float fin = act ? alpha + endt[j] : -1e30f;
        float mx = -1e30f;
        #pragma unroll
        for (int i = 0; i < NC; i++) mx = fmaxf(mx, __shfl(fin, i));
        float s = 0.f;
        #pragma unroll
        for (int i = 0; i < NC; i++) s += __expf(__shfl(fin, i) - mx);
        float den = mx + __logf(s);
        if (j == 0) {
            int last_idx = msum - 1;
            float numer = num + start[lb[0]] + emb_[lb[0]] + endt[lb[last_idx]];
            llh[b] = numer - den;
        }
    } else {
        const int b = blockIdx.x - BB;
        float tcol[NC];
        #pragma unroll
        for (int i = 0; i < NC; i++) tcol[i] = act ? trans[i * NC + j] : 0.f;
        const float* emb_ = em + (long)b * SS * NC;
        const int* mk = mask + b * SS;
        float score = act ? (start[j] + emb_[j]) : -1e30f;

        for (int t = 1; t < SS; t++) {
            float best = 0.f;
            int bi = 0;
            #pragma unroll
            for (int i = 0; i < NC; i++) {
                float vv = __shfl(score, i) + tcol[i];
                if (i == 0 || vv > best) { best = vv; bi = i; }   // first-max (jnp.argmax)
            }
            int m = mk[t];
            float nxt = best + (act ? emb_[t * NC + j] : 0.f);
            if (act) {
                if (m > 0) { score = nxt; bp[t][j] = (unsigned char)bi; }
                else       { bp[t][j] = (unsigned char)j; }
            }
        }
        float fin = act ? score + endt[j] : -1e30f;
        float bestf = 0.f;
        int last = 0;
        #pragma unroll
        for (int i = 0; i < NC; i++) {
            float vv = __shfl(fin, i);
            if (i == 0 || vv > bestf) { bestf = vv; last = i; }
        }
        __syncthreads();
        if (j == 0) {
            int cur = last;
            outp[1 + (long)b * SS + (SS - 1)] = (float)cur;
            for (int t = SS - 1; t >= 1; t--) {
                cur = bp[t][cur];
                outp[1 + (long)b * SS + (t - 1)] = (float)cur;
            }
        }
    }
}

__global__ __launch_bounds__(64) void loss_k(const float* __restrict__ llh, float* __restrict__ out) {
    int j = threadIdx.x;
    float v = llh[j];
    for (int o = 32; o > 0; o >>= 1) v += __shfl_down(v, o);
    if (j == 0) out[0] = -v / 64.0f;
}

extern "C" void kernel_launch(void* const* d_in, const int* in_sizes, int n_in,
                              void* d_out, int out_size, void* d_ws, size_t ws_size,
                              hipStream_t stream) {
    const int*   tok    = (const int*)d_in[0];
    const int*   lab    = (const int*)d_in[1];
    const int*   msk    = (const int*)d_in[2];
    const float* emb    = (const float*)d_in[3];
    const float* w_ih0  = (const float*)d_in[4];
    const float* w_hh0  = (const float*)d_in[5];
    const float* b_ih0  = (const float*)d_in[6];
    const float* b_hh0  = (const float*)d_in[7];
    const float* w_ih1  = (const float*)d_in[8];
    const float* w_hh1  = (const float*)d_in[9];
    const float* b_ih1  = (const float*)d_in[10];
    const float* b_hh1  = (const float*)d_in[11];
    const float* clsw   = (const float*)d_in[12];
    const float* clsb   = (const float*)d_in[13];
    const float* startt = (const float*)d_in[14];
    const float* endt   = (const float*)d_in[15];
    const float* transm = (const float*)d_in[16];
    float* out = (float*)d_out;

    // ---- workspace carve (f32 units); ~193 MB ----
    size_t nH8  = (size_t)BB * SS * 512 / 4;        // int8 H0
    size_t nHh  = (size_t)BB * SS * 512 / 2;        // f16 H1
    size_t nXG  = (size_t)2 * BB * SS * G4 / 2;     // f16 xg, both dirs, full S
    size_t nWQ  = (size_t)2 * 16 * 1024 * 4;        // whh int8 (uints) per layer
    size_t nW4  = (size_t)2 * 7 * 1024 * 2;         // whh int4 (uints) per layer
    size_t nSW  = (size_t)2 * 1024;
    size_t nWQ1 = (size_t)2048 * 512 / 4;
    size_t nWQ0 = (size_t)2048 * 128 / 4;
    size_t nE8  = (size_t)VV * 128 / 4;
    size_t nEM  = (size_t)BB * SS * NC;

    float* H08f = (float*)d_ws;
    float* H1f  = H08f + nH8;
    float* XGf  = H1f + nHh;
    float* WQ0  = XGf + nXG;
    float* WQ1w = WQ0 + nWQ;
    float* W40  = WQ1w + nWQ;
    float* W41  = W40 + nW4;
    float* SW0  = W41 + nW4;
    float* SW1  = SW0 + nSW;
    float* S40  = SW1 + nSW;
    float* S41  = S40 + nSW;
    float* WQI1 = S41 + nSW;
    float* SWI1 = WQI1 + nWQ1;
    float* WQI0 = SWI1 + 2048;
    float* SWI0 = WQI0 + nWQ0;
    float* EMB8 = SWI0 + 2048;
    float* SA   = EMB8 + nE8;
    float* EM   = SA + VV;
    float* LLH  = EM + nEM;

    unsigned char* H08   = (unsigned char*)H08f;
    ushort*        H1h   = (ushort*)H1f;
    ushort*        XG    = (ushort*)XGf;
    unsigned char* WQI1b = (unsigned char*)WQI1;
    unsigned char* WQI0b = (unsigned char*)WQI0;
    unsigned char* EMB8b = (unsigned char*)EMB8;

    // ---- fused preprocessing: one dispatch ----
    preproc_k<<<4 * 2048 + VV, 64, 0, stream>>>(
        w_hh0, w_hh1, w_ih1, w_ih0, emb,
        (uint*)WQ0, (uint*)W40, SW0, S40,
        (uint*)WQ1w, (uint*)W41, SW1, S41,
        WQI1b, SWI1, WQI0b, SWI0, EMB8b, SA);

    dim3 gg(BB * SS / 128, G4 / 128, 2);   // (256, 8, 2)
    dim3 rg(BB, 2);                         // 128 blocks, 1024 threads

    // ---- layer 0: full-S gemm, then full-S scan (emits int8 H0) ----
    gemm8e_k<<<gg, 1024, 0, stream>>>(EMB8b, tok, WQI0b, SWI0, SA, b_ih0, XG);
    lstm_qscan<<<rg, 1024, 0, stream>>>(XG, (const uint*)WQ0, (const uint*)W40,
                                        SW0, S40, b_hh0, H1h, H08, 1);
    // ---- layer 1: full-S gemm from H08, then full-S scan (emits f16 H1) ----
    gemm8_k<<<gg, 1024, 0, stream>>>(H08, WQI1b, SWI1, b_ih1, XG);
    lstm_qscan<<<rg, 1024, 0, stream>>>(XG, (const uint*)WQ1w, (const uint*)W41,
                                        SW1, S41, b_hh1, H1h, H08, 0);

    // ---- tail ----
    emissions_k16<<<((BB * SS * NC) + 255) / 256, 256, 0, stream>>>(H1h, clsw, clsb, EM);
    crfvit_k<<<2 * BB, 64, 0, stream>>>(EM, lab, msk, startt, endt, transm, LLH, out);
    loss_k<<<1, 64, 0, stream>>>(LLH, out);
}

// Round 28
// 1819.762 us; speedup vs baseline: 1.0603x; 1.0478x over previous
//
#include <hip/hip_runtime.h>
#include <math.h>

#define BB 64      // batch
#define SS 512     // seq len
#define HH 256     // hidden
#define NC 9       // classes
#define G4 1024    // 4*H gates (one direction)
#define VV 30000   // vocab

#define KLQ 9      // int8 k16 chunks cached in LDS = 144 KB; 7 streamed as int4

typedef _Float16 half2v __attribute__((ext_vector_type(2)));

// ---------- activations ----------
__device__ __forceinline__ float sigf(float x) {
    return 1.0f / (1.0f + __expf(-x));
}
__device__ __forceinline__ float tanhfast(float x) {
    float a = fabsf(x);
    float e = __expf(-2.0f * a);
    float t = (1.0f - e) / (1.0f + e);
    return copysignf(t, x);
}
__device__ __forceinline__ int dot16q(uint4 w, uint4 h, int acc) {
    acc = __builtin_amdgcn_sdot4((int)w.x, (int)h.x, acc, false);
    acc = __builtin_amdgcn_sdot4((int)w.y, (int)h.y, acc, false);
    acc = __builtin_amdgcn_sdot4((int)w.z, (int)h.z, acc, false);
    acc = __builtin_amdgcn_sdot4((int)w.w, (int)h.w, acc, false);
    return acc;
}
__device__ __forceinline__ ushort f16b(float x) {
    return __builtin_bit_cast(ushort, (_Float16)x);
}
__device__ __forceinline__ int pad4(int r) { return r + (r >> 3); }

// LDS-only barrier: order LDS writes->reads without draining vmcnt.
__device__ __forceinline__ void ldsbar() {
    asm volatile("s_waitcnt lgkmcnt(0)" ::: "memory");
    __builtin_amdgcn_s_barrier();
}

// ---------- preprocessing device bodies (proven) ----------
__device__ void quant_whh_dev(const float* __restrict__ whh, uint* __restrict__ wTq,
                              uint* __restrict__ wTq4,
                              float* __restrict__ swf, float* __restrict__ swf4, int row) {
    const int t = threadIdx.x;
    float4 v = *(const float4*)(whh + (long)row * 256 + t * 4);
    float mloc = fmaxf(fmaxf(fabsf(v.x), fabsf(v.y)), fmaxf(fabsf(v.z), fabsf(v.w)));
    float mx = mloc;
    #pragma unroll
    for (int o = 32; o > 0; o >>= 1) mx = fmaxf(mx, __shfl_xor(mx, o));
    const int dir = row >> 10, j = row & 1023;
    {
        float inv = (mx > 0.f) ? 127.f / mx : 0.f;
        int q0 = (int)rintf(v.x * inv) & 255;
        int q1 = (int)rintf(v.y * inv) & 255;
        int q2 = (int)rintf(v.z * inv) & 255;
        int q3 = (int)rintf(v.w * inv) & 255;
        uint u = (uint)q0 | ((uint)q1 << 8) | ((uint)q2 << 16) | ((uint)q3 << 24);
        const int kc = t >> 2, l4 = t & 3;
        wTq[(((long)(dir * 16 + kc) * 1024 + j) << 2) + l4] = u;
    }
    float m4 = (t >= 36) ? mloc : 0.f;
    #pragma unroll
    for (int o = 32; o > 0; o >>= 1) m4 = fmaxf(m4, __shfl_xor(m4, o));
    float inv4 = (m4 > 0.f) ? 7.f / m4 : 0.f;
    int n0 = (int)rintf(v.x * inv4) & 0xF;
    int n1 = (int)rintf(v.y * inv4) & 0xF;
    int n2 = (int)rintf(v.z * inv4) & 0xF;
    int n3 = (int)rintf(v.w * inv4) & 0xF;
    uint part = (uint)n0 | ((uint)n1 << 8) | ((uint)n2 << 16) | ((uint)n3 << 24);
    uint other = __shfl(part, t ^ 1);
    if (!(t & 1) && t >= 36) {
        uint u = part | (other << 4);
        int m = t >> 1;
        int cc = (m >> 1) - 9;
        int pos = m & 1;
        wTq4[(((long)(dir * 7 + cc) * 1024 + j) << 1) + pos] = u;
    }
    if (t == 0) {
        swf[row]  = (mx > 0.f) ? (mx / 127.f) * (1.f / 127.f) : 0.f;
        swf4[row] = (m4 > 0.f) ? (m4 / 7.f) * (1.f / 127.f) * (1.f / 16.f) : 0.f;
    }
}

template <int NP>
__device__ void quant_rows_dev(const float* __restrict__ in, unsigned char* __restrict__ out,
                               float* __restrict__ sc, int mode, int row) {
    const int t = threadIdx.x;
    const int K = NP * 64;
    const float* src = in + (long)row * K + t * NP;
    float v[NP];
    float mx = 0.f;
    #pragma unroll
    for (int i = 0; i < NP; i++) { v[i] = src[i]; mx = fmaxf(mx, fabsf(v[i])); }
    #pragma unroll
    for (int o = 32; o > 0; o >>= 1) mx = fmaxf(mx, __shfl_xor(mx, o));
    float inv = (mx > 0.f) ? 127.f / mx : 0.f;
    unsigned char q[NP];
    #pragma unroll
    for (int i = 0; i < NP; i++) q[i] = (unsigned char)((int)rintf(v[i] * inv) & 255);
    unsigned char* dst = out + (long)row * K + t * NP;
    if (NP == 2) {
        *(ushort*)dst = *(ushort*)q;
    } else {
        *(uint*)dst = *(uint*)q;
        *(uint*)(dst + 4) = *(uint*)(q + 4);
    }
    if (t == 0) sc[row] = (mx <= 0.f) ? 0.f
                        : (mode == 0 ? mx / 127.f : mx / (127.f * 127.f));
}

// ---------- fused preprocessing: one dispatch, role by blockIdx ----------
__global__ __launch_bounds__(64) void preproc_k(
    const float* __restrict__ whh0, const float* __restrict__ whh1,
    const float* __restrict__ wih1, const float* __restrict__ wih0,
    const float* __restrict__ emb,
    uint* WQ0, uint* W40, float* SW0, float* S40,
    uint* WQ1, uint* W41, float* SW1, float* S41,
    unsigned char* WQI1, float* SWI1,
    unsigned char* WQI0, float* SWI0,
    unsigned char* EMB8, float* SA)
{
    int bid = blockIdx.x;
    if (bid < 2048) { quant_whh_dev(whh0, WQ0, W40, SW0, S40, bid); return; }
    bid -= 2048;
    if (bid < 2048) { quant_whh_dev(whh1, WQ1, W41, SW1, S41, bid); return; }
    bid -= 2048;
    if (bid < 2048) { quant_rows_dev<8>(wih1, WQI1, SWI1, 1, bid); return; }
    bid -= 2048;
    if (bid < 2048) { quant_rows_dev<2>(wih0, WQI0, SWI0, 0, bid); return; }
    bid -= 2048;
    quant_rows_dev<2>(emb, EMB8, SA, 0, bid);
}

// ---------- L0 gemm, full S, both dirs (proven round-25) ----------
__global__ __launch_bounds__(1024, 2) void gemm8e_k(
    const unsigned char* __restrict__ A8, const int* __restrict__ tok,
    const unsigned char* __restrict__ Wq, const float* __restrict__ sw,
    const float* __restrict__ swA, const float* __restrict__ bias,
    ushort* __restrict__ xg)
{
    __shared__ uint4 As[144], Bs[144];
    const int tid = threadIdx.x;
    const int m0 = blockIdx.x * 128;
    const int n0 = blockIdx.y * 128;
    const int d  = blockIdx.z;
    const unsigned char* W = Wq + (size_t)d * 1024 * 128;
    const float* swd = sw + d * 1024;
    const float* bd  = bias + d * 1024;
    ushort* outd = xg + (size_t)d * BB * SS * G4;

    const int lr = tid & 127;
    const int lpad = lr + (lr >> 3);
    const bool isA = tid < 128, isB = (tid >= 128 && tid < 256);
    const uint4* Ap = isA ? (const uint4*)(A8 + (long)tok[m0 + lr] * 128) : nullptr;
    const uint4* Wp = isB ? (const uint4*)(W + (long)(n0 + lr) * 128) : nullptr;
    const int tr = tid >> 5, tn = tid & 31;

    int acc[4][4];
    #pragma unroll
    for (int i = 0; i < 4; i++)
        #pragma unroll
        for (int j = 0; j < 4; j++) acc[i][j] = 0;

    #pragma unroll 1
    for (int k0 = 0; k0 < 8; k0++) {
        if (isA) As[lpad] = Ap[k0];
        else if (isB) Bs[lpad] = Wp[k0];
        __syncthreads();
        uint4 a[4], w[4];
        #pragma unroll
        for (int i = 0; i < 4; i++) {
            a[i] = As[pad4(tr * 4 + i)];
            w[i] = Bs[pad4(tn * 4 + i)];
        }
        #pragma unroll
        for (int i = 0; i < 4; i++)
            #pragma unroll
            for (int j = 0; j < 4; j++)
                acc[i][j] = dot16q(w[j], a[i], acc[i][j]);
        __syncthreads();
    }

    float sA[4];
    #pragma unroll
    for (int i = 0; i < 4; i++) sA[i] = swA[tok[m0 + tr * 4 + i]];
    float sW[4], bs[4];
    #pragma unroll
    for (int j = 0; j < 4; j++) {
        sW[j] = swd[n0 + tn * 4 + j];
        bs[j] = bd[n0 + tn * 4 + j];
    }
    #pragma unroll
    for (int i = 0; i < 4; i++) {
        ushort4 o;
        #pragma unroll
        for (int j = 0; j < 4; j++) {
            float r = fmaf((float)acc[i][j] * sA[i], sW[j], bs[j]);
            ((ushort*)&o)[j] = f16b(r);
        }
        *(ushort4*)(outd + (long)(m0 + tr * 4 + i) * G4 + n0 + tn * 4) = o;
    }
}

// ---------- L1 gemm, full S, both dirs (proven round-25) ----------
__global__ __launch_bounds__(1024, 2) void gemm8_k(
    const unsigned char* __restrict__ A8, const unsigned char* __restrict__ Wq,
    const float* __restrict__ sw, const float* __restrict__ bias,
    ushort* __restrict__ xg)
{
    __shared__ uint4 As[144], Bs[144];
    const int tid = threadIdx.x;
    const int m0 = blockIdx.x * 128;
    const int n0 = blockIdx.y * 128;
    const int d  = blockIdx.z;
    const unsigned char* W = Wq + (size_t)d * 1024 * 512;
    const float* swd = sw + d * 1024;
    const float* bd  = bias + d * 1024;
    ushort* outd = xg + (size_t)d * BB * SS * G4;

    const int lr = tid & 127;
    const int lpad = lr + (lr >> 3);
    const bool isA = tid < 128, isB = (tid >= 128 && tid < 256);
    const uint4* Ap = isA ? (const uint4*)(A8 + (long)(m0 + lr) * 512) : nullptr;
    const uint4* Wp = isB ? (const uint4*)(W + (long)(n0 + lr) * 512) : nullptr;
    const int tr = tid >> 5, tn = tid & 31;

    int acc[4][4];
    #pragma unroll
    for (int i = 0; i < 4; i++)
        #pragma unroll
        for (int j = 0; j < 4; j++) acc[i][j] = 0;

    #pragma unroll 1
    for (int k0 = 0; k0 < 32; k0++) {
        if (isA) As[lpad] = Ap[k0];
        else if (isB) Bs[lpad] = Wp[k0];
        __syncthreads();
        uint4 a[4], w[4];
        #pragma unroll
        for (int i = 0; i < 4; i++) {
            a[i] = As[pad4(tr * 4 + i)];
            w[i] = Bs[pad4(tn * 4 + i)];
        }
        #pragma unroll
        for (int i = 0; i < 4; i++)
            #pragma unroll
            for (int j = 0; j < 4; j++)
                acc[i][j] = dot16q(w[j], a[i], acc[i][j]);
        __syncthreads();
    }

    #pragma unroll
    for (int i = 0; i < 4; i++) {
        ushort4 o;
        #pragma unroll
        for (int j = 0; j < 4; j++) {
            float r = fmaf((float)acc[i][j], swd[n0 + tn * 4 + j], bd[n0 + tn * 4 + j]);
            ((ushort*)&o)[j] = f16b(r);
        }
        *(ushort4*)(outd + (long)(m0 + tr * 4 + i) * G4 + n0 + tn * 4) = o;
    }
}

// ---------- LSTM scan v2: 512 threads, 2 gate rows/thread ----------
// LDS-issue bound fix: hq broadcast reads (16 x b128) shared across both rows;
// per-CU LDS instructions drop from 16w x 25 to 8w x 34 (-32%).
// Numerics identical to round-27 (same quant, same FP order).
__global__ __launch_bounds__(512, 2) void lstm_qscan2(
    const ushort* __restrict__ xg,    // [2][B*S][1024] f16, natural t order
    const uint* __restrict__ wTq,     // int8 [2][16][1024][4] (chunks 0..8 used)
    const uint* __restrict__ wTq4,    // int4 [2][7][1024][2]
    const float* __restrict__ swf,    // [2][1024]
    const float* __restrict__ swf4,   // [2][1024] (includes /16)
    const float* __restrict__ bhh2,   // [2][1024]
    ushort* __restrict__ hout,        // f16 H (layer 1)
    unsigned char* __restrict__ hout8,// int8 H (layer 0)
    int doW8)
{
    const int b = blockIdx.x;
    const int d = blockIdx.y;
    const int t = threadIdx.x;             // 0..511; owns gate rows t and t+512
    const ushort* xgd = xg + ((size_t)d * BB * SS + (size_t)b * SS) * G4;
    const uint4* wTd = (const uint4*)wTq + (long)d * 16 * 1024;
    const uint2* w4d = (const uint2*)wTq4 + (long)d * 7 * 1024;

    __shared__ __align__(16) uint hq[2][64];   // int8 h packed
    __shared__ float gl[G4];                   // gate exchange
    __shared__ uint4 lwq[KLQ * 1024];          // 144 KB int8 weight cache

    #pragma unroll
    for (int kc = 0; kc < KLQ; kc++) {
        lwq[kc * 1024 + t]       = wTd[(long)kc * 1024 + t];
        lwq[kc * 1024 + t + 512] = wTd[(long)kc * 1024 + t + 512];
    }

    const float bj0 = bhh2[d * G4 + t];
    const float bj1 = bhh2[d * G4 + t + 512];
    const float s80 = swf[d * G4 + t];
    const float s81 = swf[d * G4 + t + 512];
    const float s40 = swf4[d * G4 + t];
    const float s41 = swf4[d * G4 + t + 512];
    float c_reg = 0.f;
    if (t < HH) ((char*)hq[0])[t] = 0;
    __syncthreads();

    #pragma unroll 1
    for (int tc = 0; tc < SS; ++tc) {
        const int rb = tc & 1;
        const int tt = d ? (SS - 1 - tc) : tc;
        const uint4* hc = (const uint4*)hq[rb];
        int i80 = 0, i81 = 0;
        #pragma unroll
        for (int kc = 0; kc < KLQ; kc++) {
            uint4 h = hc[kc];                        // broadcast, shared
            i80 = dot16q(lwq[kc * 1024 + t],       h, i80);
            i81 = dot16q(lwq[kc * 1024 + t + 512], h, i81);
        }
        int i40 = 0, i41 = 0;
        #pragma unroll
        for (int cc = 0; cc < 7; cc++) {
            uint4 h = hc[9 + cc];                    // broadcast, shared
            uint2 u0 = w4d[(long)cc * 1024 + t];
            uint2 u1 = w4d[(long)cc * 1024 + t + 512];
            i40 = __builtin_amdgcn_sdot4((int)((u0.x & 0x0F0F0F0Fu) << 4), (int)h.x, i40, false);
            i40 = __builtin_amdgcn_sdot4((int)(u0.x & 0xF0F0F0F0u),        (int)h.y, i40, false);
            i40 = __builtin_amdgcn_sdot4((int)((u0.y & 0x0F0F0F0Fu) << 4), (int)h.z, i40, false);
            i40 = __builtin_amdgcn_sdot4((int)(u0.y & 0xF0F0F0F0u),        (int)h.w, i40, false);
            i41 = __builtin_amdgcn_sdot4((int)((u1.x & 0x0F0F0F0Fu) << 4), (int)h.x, i41, false);
            i41 = __builtin_amdgcn_sdot4((int)(u1.x & 0xF0F0F0F0u),        (int)h.y, i41, false);
            i41 = __builtin_amdgcn_sdot4((int)((u1.y & 0x0F0F0F0Fu) << 4), (int)h.z, i41, false);
            i41 = __builtin_amdgcn_sdot4((int)(u1.y & 0xF0F0F0F0u),        (int)h.w, i41, false);
        }

        float xv0 = (float)__builtin_bit_cast(_Float16, xgd[(long)tt * G4 + t]);
        float xv1 = (float)__builtin_bit_cast(_Float16, xgd[(long)tt * G4 + t + 512]);
        gl[t]       = fmaf((float)i40, s40, fmaf((float)i80, s80, xv0 + bj0));
        gl[t + 512] = fmaf((float)i41, s41, fmaf((float)i81, s81, xv1 + bj1));
        ldsbar();                            // order gl writes -> reads
        if (t < HH) {
            float gi = gl[t], gf = gl[t + 256], gg = gl[t + 512], go = gl[t + 768];
            c_reg = sigf(gf) * c_reg + sigf(gi) * tanhfast(gg);
            float h = sigf(go) * tanhfast(c_reg);
            int qh = __float2int_rn(h * 127.f);
            ((char*)hq[rb ^ 1])[t] = (char)qh;
            if (doW8) hout8[((long)(b * SS + tt)) * 512 + d * HH + t] = (unsigned char)(char)qh;
            else      hout [((long)(b * SS + tt)) * 512 + d * HH + t] = f16b(h);
        }
        ldsbar();                            // order hq writes -> next-step reads
    }
}

// ---------- emissions (f16 h) ----------
__global__ __launch_bounds__(256) void emissions_k16(
    const ushort* __restrict__ h1, const float* __restrict__ clsw,
    const float* __restrict__ clsb, float* __restrict__ em)
{
    long u = (long)blockIdx.x * 256 + threadIdx.x;
    if (u >= (long)BB * SS * NC) return;
    int c = (int)(u % NC);
    long m = u / NC;
    const uint* hr = (const uint*)(h1 + m * 512);
    const float2* wr = (const float2*)(clsw + (long)c * 512);
    float s0 = 0, s1 = 0;
    #pragma unroll 8
    for (int q = 0; q < 256; q += 2) {
        half2v h0 = __builtin_bit_cast(half2v, hr[q]);
        half2v h1v = __builtin_bit_cast(half2v, hr[q + 1]);
        float2 w0 = wr[q], w1 = wr[q + 1];
        s0 += (float)h0.x * w0.x + (float)h0.y * w0.y;
        s1 += (float)h1v.x * w1.x + (float)h1v.y * w1.y;
    }
    em[u] = s0 + s1 + clsb[c];
}

// ---------- fused CRF llh (blocks 0..63) + Viterbi (blocks 64..127) ----------
__global__ __launch_bounds__(64) void crfvit_k(
    const float* __restrict__ em, const int* __restrict__ labels,
    const int* __restrict__ mask, const float* __restrict__ start,
    const float* __restrict__ endt, const float* __restrict__ trans,
    float* __restrict__ llh, float* __restrict__ outp)
{
    __shared__ unsigned char bp[SS][NC];
    const int j = threadIdx.x;
    const bool act = j < NC;
    if (blockIdx.x < BB) {
        const int b = blockIdx.x;
        float tcol[NC];
        #pragma unroll
        for (int i = 0; i < NC; i++) tcol[i] = act ? trans[i * NC + j] : 0.f;
        const float* emb_ = em + (long)b * SS * NC;
        const int* lb = labels + b * SS;
        const int* mk = mask + b * SS;
        float alpha = act ? (start[j] + emb_[j]) : -1e30f;

        float num = 0.f;
        int msum = 0;
        for (int t = j; t < SS; t += 64) msum += (mk[t] != 0);
        for (int t = 1 + j; t < SS; t += 64) {
            float m = (float)mk[t];
            num += m * (trans[lb[t - 1] * NC + lb[t]] + emb_[t * NC + lb[t]]);
        }
        for (int o = 32; o > 0; o >>= 1) {
            num  += __shfl_down(num, o);
            msum += __shfl_down(msum, o);
        }
        msum = __shfl(msum, 0);

        for (int t = 1; t < SS; t++) {
            int m = mk[t];
            float emj = act ? emb_[t * NC + j] : 0.f;
            float v[NC];
            float mx = -1e30f;
            #pragma unroll
            for (int i = 0; i < NC; i++) {
                v[i] = __shfl(alpha, i) + tcol[i];
                mx = fmaxf(mx, v[i]);
            }
            float sum = 0.f;
            #pragma unroll
            for (int i = 0; i < NC; i++) sum += __expf(v[i] - mx);
            float nxt = mx + __logf(sum) + emj;
            if (m > 0 && act) alpha = nxt;
        }
        float fin = act ? alpha + endt[j] : -1e30f;
        float mx = -1e30f;
        #pragma unroll
        for (int i = 0; i < NC; i++) mx = fmaxf(mx, __shfl(fin, i));
        float s = 0.f;
        #pragma unroll
        for (int i = 0; i < NC; i++) s += __expf(__shfl(fin, i) - mx);
        float den = mx + __logf(s);
        if (j == 0) {
            int last_idx = msum - 1;
            float numer = num + start[lb[0]] + emb_[lb[0]] + endt[lb[last_idx]];
            llh[b] = numer - den;
        }
    } else {
        const int b = blockIdx.x - BB;
        float tcol[NC];
        #pragma unroll
        for (int i = 0; i < NC; i++) tcol[i] = act ? trans[i * NC + j] : 0.f;
        const float* emb_ = em + (long)b * SS * NC;
        const int* mk = mask + b * SS;
        float score = act ? (start[j] + emb_[j]) : -1e30f;

        for (int t = 1; t < SS; t++) {
            float best = 0.f;
            int bi = 0;
            #pragma unroll
            for (int i = 0; i < NC; i++) {
                float vv = __shfl(score, i) + tcol[i];
                if (i == 0 || vv > best) { best = vv; bi = i; }   // first-max (jnp.argmax)
            }
            int m = mk[t];
            float nxt = best + (act ? emb_[t * NC + j] : 0.f);
            if (act) {
                if (m > 0) { score = nxt; bp[t][j] = (unsigned char)bi; }
                else       { bp[t][j] = (unsigned char)j; }
            }
        }
        float fin = act ? score + endt[j] : -1e30f;
        float bestf = 0.f;
        int last = 0;
        #pragma unroll
        for (int i = 0; i < NC; i++) {
            float vv = __shfl(fin, i);
            if (i == 0 || vv > bestf) { bestf = vv; last = i; }
        }
        __syncthreads();
        if (j == 0) {
            int cur = last;
            outp[1 + (long)b * SS + (SS - 1)] = (float)cur;
            for (int t = SS - 1; t >= 1; t--) {
                cur = bp[t][cur];
                outp[1 + (long)b * SS + (t - 1)] = (float)cur;
            }
        }
    }
}

__global__ __launch_bounds__(64) void loss_k(const float* __restrict__ llh, float* __restrict__ out) {
    int j = threadIdx.x;
    float v = llh[j];
    for (int o = 32; o > 0; o >>= 1) v += __shfl_down(v, o);
    if (j == 0) out[0] = -v / 64.0f;
}

extern "C" void kernel_launch(void* const* d_in, const int* in_sizes, int n_in,
                              void* d_out, int out_size, void* d_ws, size_t ws_size,
                              hipStream_t stream) {
    const int*   tok    = (const int*)d_in[0];
    const int*   lab    = (const int*)d_in[1];
    const int*   msk    = (const int*)d_in[2];
    const float* emb    = (const float*)d_in[3];
    const float* w_ih0  = (const float*)d_in[4];
    const float* w_hh0  = (const float*)d_in[5];
    const float* b_ih0  = (const float*)d_in[6];
    const float* b_hh0  = (const float*)d_in[7];
    const float* w_ih1  = (const float*)d_in[8];
    const float* w_hh1  = (const float*)d_in[9];
    const float* b_ih1  = (const float*)d_in[10];
    const float* b_hh1  = (const float*)d_in[11];
    const float* clsw   = (const float*)d_in[12];
    const float* clsb   = (const float*)d_in[13];
    const float* startt = (const float*)d_in[14];
    const float* endt   = (const float*)d_in[15];
    const float* transm = (const float*)d_in[16];
    float* out = (float*)d_out;

    // ---- workspace carve (f32 units); ~193 MB ----
    size_t nH8  = (size_t)BB * SS * 512 / 4;        // int8 H0
    size_t nHh  = (size_t)BB * SS * 512 / 2;        // f16 H1
    size_t nXG  = (size_t)2 * BB * SS * G4 / 2;     // f16 xg, both dirs, full S
    size_t nWQ  = (size_t)2 * 16 * 1024 * 4;        // whh int8 (uints) per layer
    size_t nW4  = (size_t)2 * 7 * 1024 * 2;         // whh int4 (uints) per layer
    size_t nSW  = (size_t)2 * 1024;
    size_t nWQ1 = (size_t)2048 * 512 / 4;
    size_t nWQ0 = (size_t)2048 * 128 / 4;
    size_t nE8  = (size_t)VV * 128 / 4;
    size_t nEM  = (size_t)BB * SS * NC;

    float* H08f = (float*)d_ws;
    float* H1f  = H08f + nH8;
    float* XGf  = H1f + nHh;
    float* WQ0  = XGf + nXG;
    float* WQ1w = WQ0 + nWQ;
    float* W40  = WQ1w + nWQ;
    float* W41  = W40 + nW4;
    float* SW0  = W41 + nW4;
    float* SW1  = SW0 + nSW;
    float* S40  = SW1 + nSW;
    float* S41  = S40 + nSW;
    float* WQI1 = S41 + nSW;
    float* SWI1 = WQI1 + nWQ1;
    float* WQI0 = SWI1 + 2048;
    float* SWI0 = WQI0 + nWQ0;
    float* EMB8 = SWI0 + 2048;
    float* SA   = EMB8 + nE8;
    float* EM   = SA + VV;
    float* LLH  = EM + nEM;

    unsigned char* H08   = (unsigned char*)H08f;
    ushort*        H1h   = (ushort*)H1f;
    ushort*        XG    = (ushort*)XGf;
    unsigned char* WQI1b = (unsigned char*)WQI1;
    unsigned char* WQI0b = (unsigned char*)WQI0;
    unsigned char* EMB8b = (unsigned char*)EMB8;

    // ---- fused preprocessing: one dispatch ----
    preproc_k<<<4 * 2048 + VV, 64, 0, stream>>>(
        w_hh0, w_hh1, w_ih1, w_ih0, emb,
        (uint*)WQ0, (uint*)W40, SW0, S40,
        (uint*)WQ1w, (uint*)W41, SW1, S41,
        WQI1b, SWI1, WQI0b, SWI0, EMB8b, SA);

    dim3 gg(BB * SS / 128, G4 / 128, 2);   // (256, 8, 2)
    dim3 rg(BB, 2);                         // 128 blocks, 512 threads

    // ---- layer 0: full-S gemm, then full-S scan (emits int8 H0) ----
    gemm8e_k<<<gg, 1024, 0, stream>>>(EMB8b, tok, WQI0b, SWI0, SA, b_ih0, XG);
    lstm_qscan2<<<rg, 512, 0, stream>>>(XG, (const uint*)WQ0, (const uint*)W40,
                                        SW0, S40, b_hh0, H1h, H08, 1);
    // ---- layer 1: full-S gemm from H08, then full-S scan (emits f16 H1) ----
    gemm8_k<<<gg, 1024, 0, stream>>>(H08, WQI1b, SWI1, b_ih1, XG);
    lstm_qscan2<<<rg, 512, 0, stream>>>(XG, (const uint*)WQ1w, (const uint*)W41,
                                        SW1, S41, b_hh1, H1h, H08, 0);

    // ---- tail ----
    emissions_k16<<<((BB * SS * NC) + 255) / 256, 256, 0, stream>>>(H1h, clsw, clsb, EM);
    crfvit_k<<<2 * BB, 64, 0, stream>>>(EM, lab, msk, startt, endt, transm, LLH, out);
    loss_k<<<1, 64, 0, stream>>>(LLH, out);
}